// Round 3
// baseline (506.725 us; speedup 1.0000x reference)
//
#include <hip/hip_runtime.h>
#include <cstddef>

typedef unsigned short ushort_t;
typedef __attribute__((ext_vector_type(8))) short sh8;   // 8 x bf16 bits = 4 VGPRs
typedef __attribute__((ext_vector_type(4))) float f4;    // MFMA 16x16x32 C/D
typedef __attribute__((ext_vector_type(4))) unsigned short us4;

static constexpr int Bc = 4, Cc = 512, Nc = 2048, Hc = 8, DKc = 64, O3c = 1536;
static constexpr int BHN = Bc * Hc * Nc;          // 65536
static constexpr float SCALE = 0.125f;            // DK^-0.5
static constexpr int NSPLIT_A = 2;                // apply j-split
static constexpr int NSPLIT_S = 4;                // stats i-split

__device__ __forceinline__ unsigned short f2bf(float f) {
    union { float f; unsigned u; } v; v.f = f;
    unsigned r = v.u + 0x7FFFu + ((v.u >> 16) & 1u);  // RNE
    return (unsigned short)(r >> 16);
}
__device__ __forceinline__ float bf2f(unsigned short b) {
    union { unsigned u; float f; } v; v.u = ((unsigned)b) << 16;
    return v.f;
}

// ---------------------------------------------------------------------------
// Prep A: x[b,c,n] fp32 -> xt[b,n,c] bf16 (LDS 32x32 tile transpose)
// ---------------------------------------------------------------------------
__global__ __launch_bounds__(256) void xpose_kernel(
    const float* __restrict__ x, ushort_t* __restrict__ xt)
{
    __shared__ float t[32][33];
    const int b = blockIdx.z, n0 = blockIdx.x * 32, c0 = blockIdx.y * 32;
    const int tx = threadIdx.x & 31, ty = threadIdx.x >> 5;
    const float* xb = x + (size_t)b * Cc * Nc;
#pragma unroll
    for (int r = 0; r < 4; ++r)
        t[ty + r * 8][tx] = xb[(size_t)(c0 + ty + r * 8) * Nc + n0 + tx];
    __syncthreads();
    ushort_t* xtb = xt + (size_t)b * Nc * Cc;
#pragma unroll
    for (int r = 0; r < 4; ++r)
        xtb[(size_t)(n0 + ty + r * 8) * Cc + c0 + tx] = f2bf(t[tx][ty + r * 8]);
}

// ---------------------------------------------------------------------------
// Prep B: fp32 -> bf16 bulk convert (vectorized), n4 = count/4
// ---------------------------------------------------------------------------
__global__ __launch_bounds__(256) void cvt_kernel(
    const float* __restrict__ s, ushort_t* __restrict__ d, int n4)
{
    int i = blockIdx.x * 256 + threadIdx.x;
    if (i < n4) {
        float4 v = ((const float4*)s)[i];
        us4 o = { f2bf(v.x), f2bf(v.y), f2bf(v.z), f2bf(v.w) };
        ((us4*)d)[i] = o;
    }
}

// ---------------------------------------------------------------------------
// Kernel 1: qkv projection via MFMA (unchanged from R2; passed).
// ---------------------------------------------------------------------------
__global__ __launch_bounds__(256) void qkv_kernel(
    const ushort_t* __restrict__ xt, const ushort_t* __restrict__ Wpb,
    const float* __restrict__ bp,
    ushort_t* __restrict__ q, ushort_t* __restrict__ k, ushort_t* __restrict__ vT)
{
    const int tid = threadIdx.x;
    const int wave = tid >> 6, lane = tid & 63, quad = lane >> 4, l15 = lane & 15;
    const int b = blockIdx.z;
    const int m0 = blockIdx.y * 128 + (wave & 1) * 64;   // token
    const int o0 = blockIdx.x * 128 + (wave >> 1) * 64;  // qkv feature
    const ushort_t* A  = xt  + ((size_t)b * Nc + m0) * Cc;
    const ushort_t* Bp = Wpb + (size_t)o0 * Cc;

    f4 acc[4][4];
#pragma unroll
    for (int i = 0; i < 4; ++i)
#pragma unroll
        for (int j = 0; j < 4; ++j) acc[i][j] = (f4)0.f;

    for (int kk = 0; kk < Cc; kk += 32) {
        sh8 a[4], bb[4];
#pragma unroll
        for (int mi = 0; mi < 4; ++mi)
            a[mi] = *(const sh8*)&A[(size_t)(mi * 16 + l15) * Cc + kk + quad * 8];
#pragma unroll
        for (int ni = 0; ni < 4; ++ni)
            bb[ni] = *(const sh8*)&Bp[(size_t)(ni * 16 + l15) * Cc + kk + quad * 8];
#pragma unroll
        for (int mi = 0; mi < 4; ++mi)
#pragma unroll
            for (int ni = 0; ni < 4; ++ni)
                acc[mi][ni] = __builtin_amdgcn_mfma_f32_16x16x32_bf16(
                    a[mi], bb[ni], acc[mi][ni], 0, 0, 0);
    }

    const int f  = (o0 >> 6) % 3;   // 0=q 1=k 2=v (wave-uniform)
    const int h  = o0 / 192;
    const int bh = b * Hc + h;
#pragma unroll
    for (int ni = 0; ni < 4; ++ni) {
        const int o = o0 + ni * 16 + l15;
        const int d = o & 63;
        const float bias = bp[o];
        if (f == 2) {
            ushort_t* dst = vT + ((size_t)bh * DKc + d) * Nc + m0;
#pragma unroll
            for (int mi = 0; mi < 4; ++mi) {
                us4 pk = { f2bf(acc[mi][ni][0] + bias), f2bf(acc[mi][ni][1] + bias),
                           f2bf(acc[mi][ni][2] + bias), f2bf(acc[mi][ni][3] + bias) };
                *(us4*)&dst[mi * 16 + quad * 4] = pk;
            }
        } else {
            ushort_t* dst = (f == 0 ? q : k) + ((size_t)bh * Nc + m0) * DKc + d;
#pragma unroll
            for (int mi = 0; mi < 4; ++mi)
#pragma unroll
                for (int r = 0; r < 4; ++r)
                    dst[(size_t)(mi * 16 + quad * 4 + r) * DKc] =
                        f2bf(acc[mi][ni][r] + bias);
        }
    }
}

// ---------------------------------------------------------------------------
// Kernel 2: partial column sums over an i-chunk.
// spart[split][bh][j] = sum_{i in chunk} exp(scale * q_i . k_j)
// grid (Nc/128, NSPLIT_S, B*H), block 256 (wave owns 32 j).
// ---------------------------------------------------------------------------
__global__ __launch_bounds__(256) void stats_kernel(
    const ushort_t* __restrict__ q, const ushort_t* __restrict__ k,
    float* __restrict__ spart)
{
    const int tid = threadIdx.x;
    const int wave = tid >> 6, lane = tid & 63, quad = lane >> 4, l15 = lane & 15;
    const int bh = blockIdx.z;
    const int j0 = blockIdx.x * 128 + wave * 32;
    const int ibase = blockIdx.y * (Nc / NSPLIT_S);
    const ushort_t* K = k + ((size_t)bh * Nc + j0) * DKc;
    const ushort_t* Q = q + (size_t)bh * Nc * DKc;

    sh8 aK[2][2];
#pragma unroll
    for (int mi = 0; mi < 2; ++mi)
#pragma unroll
        for (int kk = 0; kk < 2; ++kk)
            aK[mi][kk] = *(const sh8*)&K[(size_t)(mi * 16 + l15) * DKc + kk * 32 + quad * 8];

    float lsum[2][4] = {};
    for (int it = 0; it < Nc / NSPLIT_S; it += 64) {
        const int i0 = ibase + it;
        sh8 bQ[4][2];
#pragma unroll
        for (int ni = 0; ni < 4; ++ni)
#pragma unroll
            for (int kk = 0; kk < 2; ++kk)
                bQ[ni][kk] = *(const sh8*)&Q[(size_t)(i0 + ni * 16 + l15) * DKc + kk * 32 + quad * 8];
#pragma unroll
        for (int mi = 0; mi < 2; ++mi)
#pragma unroll
            for (int ni = 0; ni < 4; ++ni) {
                f4 s = (f4)0.f;
                s = __builtin_amdgcn_mfma_f32_16x16x32_bf16(aK[mi][0], bQ[ni][0], s, 0, 0, 0);
                s = __builtin_amdgcn_mfma_f32_16x16x32_bf16(aK[mi][1], bQ[ni][1], s, 0, 0, 0);
#pragma unroll
                for (int r = 0; r < 4; ++r)
                    lsum[mi][r] += __expf(s[r] * SCALE);
            }
    }
#pragma unroll
    for (int mi = 0; mi < 2; ++mi)
#pragma unroll
        for (int r = 0; r < 4; ++r) {
            float v = lsum[mi][r];
            v += __shfl_xor(v, 1); v += __shfl_xor(v, 2);
            v += __shfl_xor(v, 4); v += __shfl_xor(v, 8);
            if (l15 == 0)
                spart[((size_t)blockIdx.y * Bc * Hc + bh) * Nc + j0 + mi * 16 + quad * 4 + r] = v;
        }
}

// coef[g] = 1 / sum_splits spart[s][g]
__global__ __launch_bounds__(256) void rcp_kernel(
    const float* __restrict__ spart, float* __restrict__ coef)
{
    int g = blockIdx.x * 256 + threadIdx.x;
    float s = 0.f;
#pragma unroll
    for (int p = 0; p < NSPLIT_S; ++p) s += spart[(size_t)p * BHN + g];
    coef[g] = 1.0f / s;
}

// ---------------------------------------------------------------------------
// Kernel 3: partial PV over a j-chunk. 16 q-rows per wave.
// S^T via MFMA (A=K m=j, B=Q n=i) => lane holds 4 consecutive j => packed
// ds_write_b64 into XOR-swizzled per-wave P (conflict-free), read back as
// A-operand, PV MFMA. Partial res (bf16) per j-chunk; no __syncthreads.
// grid (Nc/64, NSPLIT_A, B*H), block 256.
// ---------------------------------------------------------------------------
__global__ __launch_bounds__(256) void apply_kernel(
    const ushort_t* __restrict__ q, const ushort_t* __restrict__ k,
    const ushort_t* __restrict__ vT, const float* __restrict__ coef,
    ushort_t* __restrict__ part0, ushort_t* __restrict__ part1)
{
    __shared__ ushort_t P[4][16][64];   // per-wave, XOR-swizzled (granule 8)
    const int tid = threadIdx.x;
    const int wave = tid >> 6, lane = tid & 63, quad = lane >> 4, l15 = lane & 15;
    const int bh = blockIdx.z, b = bh >> 3, h = bh & 7;
    const int i0 = blockIdx.x * 64 + wave * 16;
    const int jbase = blockIdx.y * (Nc / NSPLIT_A);
    const ushort_t* Q = q  + ((size_t)bh * Nc + i0) * DKc;
    const ushort_t* K = k  + (size_t)bh * Nc * DKc;
    const ushort_t* V = vT + (size_t)bh * DKc * Nc;
    const float*   cf = coef + (size_t)bh * Nc;
    ushort_t* Pw = &P[wave][0][0];
    const int swz = l15 & 7;

    sh8 bQ[2];
#pragma unroll
    for (int kk = 0; kk < 2; ++kk)
        bQ[kk] = *(const sh8*)&Q[(size_t)l15 * DKc + kk * 32 + quad * 8];

    f4 acc[4];
#pragma unroll
    for (int ni = 0; ni < 4; ++ni) acc[ni] = (f4)0.f;

    for (int jt = 0; jt < Nc / NSPLIT_A; jt += 64) {
        const int j0 = jbase + jt;
        // S^T tiles: row=j (quad*4+r), col=i (l15)
#pragma unroll
        for (int nj = 0; nj < 4; ++nj) {
            const ushort_t* Kr = &K[(size_t)(j0 + nj * 16 + l15) * DKc];
            sh8 aK0 = *(const sh8*)&Kr[quad * 8];
            sh8 aK1 = *(const sh8*)&Kr[32 + quad * 8];
            f4 s = (f4)0.f;
            s = __builtin_amdgcn_mfma_f32_16x16x32_bf16(aK0, bQ[0], s, 0, 0, 0);
            s = __builtin_amdgcn_mfma_f32_16x16x32_bf16(aK1, bQ[1], s, 0, 0, 0);
            const float4 c4 = *(const float4*)&cf[j0 + nj * 16 + quad * 4];
            unsigned p01 = (unsigned)f2bf(__expf(s[0] * SCALE) * c4.x)
                         | ((unsigned)f2bf(__expf(s[1] * SCALE) * c4.y) << 16);
            unsigned p23 = (unsigned)f2bf(__expf(s[2] * SCALE) * c4.z)
                         | ((unsigned)f2bf(__expf(s[3] * SCALE) * c4.w) << 16);
            const int jb = nj * 16 + quad * 4;
            const int addr = l15 * 64 + ((((jb >> 3) ^ swz) << 3) | (jb & 7));
            uint2 pk; pk.x = p01; pk.y = p23;
            *(uint2*)(Pw + addr) = pk;
        }
        // P: C-layout -> A-layout (m=i=l15, k=j contiguous), swizzled read
        sh8 aP[2];
#pragma unroll
        for (int kk = 0; kk < 2; ++kk) {
            const int jg = kk * 4 + quad;
            aP[kk] = *(const sh8*)(Pw + l15 * 64 + ((jg ^ swz) << 3));
        }
        // PV: B = V^T rows (n=d, k=j)
#pragma unroll
        for (int ni = 0; ni < 4; ++ni) {
            const ushort_t* Vr = &V[(size_t)(ni * 16 + l15) * Nc + j0];
            sh8 v0 = *(const sh8*)&Vr[quad * 8];
            sh8 v1 = *(const sh8*)&Vr[32 + quad * 8];
            acc[ni] = __builtin_amdgcn_mfma_f32_16x16x32_bf16(aP[0], v0, acc[ni], 0, 0, 0);
            acc[ni] = __builtin_amdgcn_mfma_f32_16x16x32_bf16(aP[1], v1, acc[ni], 0, 0, 0);
        }
    }

    ushort_t* part = blockIdx.y ? part1 : part0;
    ushort_t* dst = part + ((size_t)b * Nc + i0) * Cc + h * DKc;
#pragma unroll
    for (int ni = 0; ni < 4; ++ni)
#pragma unroll
        for (int r = 0; r < 4; ++r)
            dst[(size_t)(quad * 4 + r) * Cc + ni * 16 + l15] = f2bf(acc[ni][r]);
}

// res (== part1 in-place) = bf16( fp32(part0) + fp32(part1) ), vectorized x4
__global__ __launch_bounds__(256) void reduce_kernel(
    const ushort_t* __restrict__ p0, ushort_t* __restrict__ p1res)
{
    int i = blockIdx.x * 256 + threadIdx.x;
    us4 a = ((const us4*)p0)[i];
    us4 b = ((const us4*)p1res)[i];
    us4 o;
#pragma unroll
    for (int j = 0; j < 4; ++j)
        o[j] = f2bf(bf2f(a[j]) + bf2f(b[j]));
    ((us4*)p1res)[i] = o;
}

// ---------------------------------------------------------------------------
// Kernel 4: out[b,co,n] = res @ Wo^T + bo + x (unchanged from R2; passed)
// ---------------------------------------------------------------------------
__global__ __launch_bounds__(256) void out_kernel(
    const ushort_t* __restrict__ res, const ushort_t* __restrict__ Wob,
    const float* __restrict__ bo, const float* __restrict__ x,
    float* __restrict__ out)
{
    const int tid = threadIdx.x;
    const int wave = tid >> 6, lane = tid & 63, quad = lane >> 4, l15 = lane & 15;
    const int m0  = blockIdx.x * 128 + (wave & 1) * 64;   // global token (b*N+n)
    const int co0 = blockIdx.y * 128 + (wave >> 1) * 64;
    const ushort_t* A  = res + (size_t)m0 * Cc;
    const ushort_t* Bw = Wob + (size_t)co0 * Cc;

    f4 acc[4][4];
#pragma unroll
    for (int i = 0; i < 4; ++i)
#pragma unroll
        for (int j = 0; j < 4; ++j) acc[i][j] = (f4)0.f;

    for (int kk = 0; kk < Cc; kk += 32) {
        sh8 a[4], bb[4];
#pragma unroll
        for (int mi = 0; mi < 4; ++mi)
            a[mi] = *(const sh8*)&A[(size_t)(mi * 16 + l15) * Cc + kk + quad * 8];
#pragma unroll
        for (int ni = 0; ni < 4; ++ni)
            bb[ni] = *(const sh8*)&Bw[(size_t)(ni * 16 + l15) * Cc + kk + quad * 8];
#pragma unroll
        for (int mi = 0; mi < 4; ++mi)
#pragma unroll
            for (int ni = 0; ni < 4; ++ni)
                acc[mi][ni] = __builtin_amdgcn_mfma_f32_16x16x32_bf16(
                    a[mi], bb[ni], acc[mi][ni], 0, 0, 0);
    }

    const int b = m0 >> 11;
    const int n_base = m0 & 2047;
#pragma unroll
    for (int ni = 0; ni < 4; ++ni) {
        const int co = co0 + ni * 16 + l15;
        const float bias = bo[co];
#pragma unroll
        for (int mi = 0; mi < 4; ++mi) {
            const int n = n_base + mi * 16 + quad * 4;
            const size_t idx = ((size_t)b * Cc + co) * Nc + n;
            float4 xr = *(const float4*)&x[idx];
            float4 o;
            o.x = acc[mi][ni][0] + bias + xr.x;
            o.y = acc[mi][ni][1] + bias + xr.y;
            o.z = acc[mi][ni][2] + bias + xr.z;
            o.w = acc[mi][ni][3] + bias + xr.w;
            *(float4*)&out[idx] = o;
        }
    }
}

// ---------------------------------------------------------------------------
extern "C" void kernel_launch(void* const* d_in, const int* in_sizes, int n_in,
                              void* d_out, int out_size, void* d_ws, size_t ws_size,
                              hipStream_t stream)
{
    const float* x  = (const float*)d_in[0];
    const float* Wp = (const float*)d_in[1];
    const float* bp = (const float*)d_in[2];
    const float* Wo = (const float*)d_in[3];
    const float* bo = (const float*)d_in[4];
    float* out = (float*)d_out;

    // workspace: fp32 first, then bf16 arrays. part0 aliases xt (dead after
    // qkv_kernel); part1 aliases res (reduce_kernel adds in-place).
    float* coef  = (float*)d_ws;                              // BHN
    float* spart = coef + BHN;                                // NSPLIT_S * BHN
    ushort_t* wsb = (ushort_t*)(spart + (size_t)NSPLIT_S * BHN);
    const size_t nE = (size_t)Bc * Nc * Cc;                   // 4,194,304
    ushort_t* xt  = wsb;                 // also part0
    ushort_t* Wpb = xt  + nE;
    ushort_t* Wob = Wpb + (size_t)O3c * Cc;
    ushort_t* qw  = Wob + (size_t)Cc * Cc;
    ushort_t* kw  = qw + nE;
    ushort_t* vT  = kw + nE;
    ushort_t* res = vT + nE;             // also part1

    xpose_kernel<<<dim3(Nc / 32, Cc / 32, Bc), 256, 0, stream>>>(x, xt);
    cvt_kernel<<<dim3((O3c * Cc / 4 + 255) / 256), 256, 0, stream>>>(Wp, Wpb, O3c * Cc / 4);
    cvt_kernel<<<dim3((Cc * Cc / 4 + 255) / 256), 256, 0, stream>>>(Wo, Wob, Cc * Cc / 4);
    qkv_kernel<<<dim3(O3c / 128, Nc / 128, Bc), 256, 0, stream>>>(xt, Wpb, bp, qw, kw, vT);
    stats_kernel<<<dim3(Nc / 128, NSPLIT_S, Bc * Hc), 256, 0, stream>>>(qw, kw, spart);
    rcp_kernel<<<dim3(BHN / 256), 256, 0, stream>>>(spart, coef);
    apply_kernel<<<dim3(Nc / 64, NSPLIT_A, Bc * Hc), 256, 0, stream>>>(qw, kw, vT, coef, xt, res);
    reduce_kernel<<<dim3((int)(nE / 4 / 256)), 256, 0, stream>>>(xt, res);
    out_kernel<<<dim3(Bc * Nc / 128, Cc / 128), 256, 0, stream>>>(res, Wob, bo, x, out);
}

// Round 4
// 281.788 us; speedup vs baseline: 1.7982x; 1.7982x over previous
//
#include <hip/hip_runtime.h>
#include <cstddef>

typedef unsigned short ushort_t;
typedef __attribute__((ext_vector_type(8))) short sh8;   // 8 x bf16 bits = 4 VGPRs
typedef __attribute__((ext_vector_type(4))) float f4;    // MFMA 16x16x32 C/D
typedef __attribute__((ext_vector_type(4))) unsigned short us4;

static constexpr int Bc = 4, Cc = 512, Nc = 2048, Hc = 8, DKc = 64, O3c = 1536;
static constexpr int BHN = Bc * Hc * Nc;          // 65536
static constexpr int NSPLIT_A = 2;                // apply j-split
static constexpr int NSPLIT_S = 2;                // stats i-split
static constexpr float K2 = 0.125f * 1.44269504089f;  // scale * log2(e)

__device__ __forceinline__ unsigned short f2bf(float f) {
    union { float f; unsigned u; } v; v.f = f;
    unsigned r = v.u + 0x7FFFu + ((v.u >> 16) & 1u);  // RNE
    return (unsigned short)(r >> 16);
}
__device__ __forceinline__ float bf2f(unsigned short b) {
    union { unsigned u; float f; } v; v.u = ((unsigned)b) << 16;
    return v.f;
}
__device__ __forceinline__ unsigned fbits(float f) {
    union { float f; unsigned u; } v; v.f = f; return v.u;
}
// async global->LDS, 16B per lane; LDS dst = wave-uniform base + lane*16
__device__ __forceinline__ void gl_lds16(const ushort_t* g, ushort_t* l) {
    __builtin_amdgcn_global_load_lds(
        (const __attribute__((address_space(1))) unsigned int*)g,
        (__attribute__((address_space(3))) unsigned int*)l, 16, 0, 0);
}

// ---------------------------------------------------------------------------
// Prep A: x[b,c,n] fp32 -> xt[b,n,c] bf16 (LDS 32x32 tile transpose)
// ---------------------------------------------------------------------------
__global__ __launch_bounds__(256) void xpose_kernel(
    const float* __restrict__ x, ushort_t* __restrict__ xt)
{
    __shared__ float t[32][33];
    const int b = blockIdx.z, n0 = blockIdx.x * 32, c0 = blockIdx.y * 32;
    const int tx = threadIdx.x & 31, ty = threadIdx.x >> 5;
    const float* xb = x + (size_t)b * Cc * Nc;
#pragma unroll
    for (int r = 0; r < 4; ++r)
        t[ty + r * 8][tx] = xb[(size_t)(c0 + ty + r * 8) * Nc + n0 + tx];
    __syncthreads();
    ushort_t* xtb = xt + (size_t)b * Nc * Cc;
#pragma unroll
    for (int r = 0; r < 4; ++r)
        xtb[(size_t)(n0 + ty + r * 8) * Cc + c0 + tx] = f2bf(t[tx][ty + r * 8]);
}

// ---------------------------------------------------------------------------
// Prep B: fp32 -> bf16 bulk convert
// ---------------------------------------------------------------------------
__global__ __launch_bounds__(256) void cvt_kernel(
    const float* __restrict__ s, ushort_t* __restrict__ d, int n4)
{
    int i = blockIdx.x * 256 + threadIdx.x;
    if (i < n4) {
        float4 v = ((const float4*)s)[i];
        us4 o = { f2bf(v.x), f2bf(v.y), f2bf(v.z), f2bf(v.w) };
        ((us4*)d)[i] = o;
    }
}

// ---------------------------------------------------------------------------
// Kernel 1: qkv projection via MFMA (unchanged; passed).
// ---------------------------------------------------------------------------
__global__ __launch_bounds__(256) void qkv_kernel(
    const ushort_t* __restrict__ xt, const ushort_t* __restrict__ Wpb,
    const float* __restrict__ bp,
    ushort_t* __restrict__ q, ushort_t* __restrict__ k, ushort_t* __restrict__ vT)
{
    const int tid = threadIdx.x;
    const int wave = tid >> 6, lane = tid & 63, quad = lane >> 4, l15 = lane & 15;
    const int b = blockIdx.z;
    const int m0 = blockIdx.y * 128 + (wave & 1) * 64;
    const int o0 = blockIdx.x * 128 + (wave >> 1) * 64;
    const ushort_t* A  = xt  + ((size_t)b * Nc + m0) * Cc;
    const ushort_t* Bp = Wpb + (size_t)o0 * Cc;

    f4 acc[4][4];
#pragma unroll
    for (int i = 0; i < 4; ++i)
#pragma unroll
        for (int j = 0; j < 4; ++j) acc[i][j] = (f4)0.f;

    for (int kk = 0; kk < Cc; kk += 32) {
        sh8 a[4], bb[4];
#pragma unroll
        for (int mi = 0; mi < 4; ++mi)
            a[mi] = *(const sh8*)&A[(size_t)(mi * 16 + l15) * Cc + kk + quad * 8];
#pragma unroll
        for (int ni = 0; ni < 4; ++ni)
            bb[ni] = *(const sh8*)&Bp[(size_t)(ni * 16 + l15) * Cc + kk + quad * 8];
#pragma unroll
        for (int mi = 0; mi < 4; ++mi)
#pragma unroll
            for (int ni = 0; ni < 4; ++ni)
                acc[mi][ni] = __builtin_amdgcn_mfma_f32_16x16x32_bf16(
                    a[mi], bb[ni], acc[mi][ni], 0, 0, 0);
    }

    const int f  = (o0 >> 6) % 3;
    const int h  = o0 / 192;
    const int bh = b * Hc + h;
#pragma unroll
    for (int ni = 0; ni < 4; ++ni) {
        const int o = o0 + ni * 16 + l15;
        const int d = o & 63;
        const float bias = bp[o];
        if (f == 2) {
            ushort_t* dst = vT + ((size_t)bh * DKc + d) * Nc + m0;
#pragma unroll
            for (int mi = 0; mi < 4; ++mi) {
                us4 pk = { f2bf(acc[mi][ni][0] + bias), f2bf(acc[mi][ni][1] + bias),
                           f2bf(acc[mi][ni][2] + bias), f2bf(acc[mi][ni][3] + bias) };
                *(us4*)&dst[mi * 16 + quad * 4] = pk;
            }
        } else {
            ushort_t* dst = (f == 0 ? q : k) + ((size_t)bh * Nc + m0) * DKc + d;
#pragma unroll
            for (int mi = 0; mi < 4; ++mi)
#pragma unroll
                for (int r = 0; r < 4; ++r)
                    dst[(size_t)(mi * 16 + quad * 4 + r) * DKc] =
                        f2bf(acc[mi][ni][r] + bias);
        }
    }
}

// ---------------------------------------------------------------------------
// Kernel 2: partial column sums. spart[split][bh][j] = sum_{i chunk} 2^(s*K2)
// Wave owns 64 j; K-frags register-resident; Q streamed from global; no LDS.
// grid (Nc/256, NSPLIT_S, B*H), block 256.
// ---------------------------------------------------------------------------
__global__ __launch_bounds__(256, 2) void stats_kernel(
    const ushort_t* __restrict__ q, const ushort_t* __restrict__ k,
    float* __restrict__ spart)
{
    const int tid = threadIdx.x;
    const int wave = tid >> 6, lane = tid & 63, quad = lane >> 4, l15 = lane & 15;
    const int bh = blockIdx.z;
    const int j0 = blockIdx.x * 256 + wave * 64;
    const int ibase = blockIdx.y * (Nc / NSPLIT_S);
    const ushort_t* K = k + ((size_t)bh * Nc + j0) * DKc;
    const ushort_t* Q = q + (size_t)bh * Nc * DKc;

    sh8 aK[4][2];
#pragma unroll
    for (int mj = 0; mj < 4; ++mj)
#pragma unroll
        for (int kk = 0; kk < 2; ++kk)
            aK[mj][kk] = *(const sh8*)&K[(size_t)(mj * 16 + l15) * DKc + kk * 32 + quad * 8];

    float lsum[4][4] = {};
    for (int it = 0; it < Nc / NSPLIT_S; it += 64) {
        const int i0 = ibase + it;
        sh8 bQ[4][2];
#pragma unroll
        for (int ni = 0; ni < 4; ++ni)
#pragma unroll
            for (int kk = 0; kk < 2; ++kk)
                bQ[ni][kk] = *(const sh8*)&Q[(size_t)(i0 + ni * 16 + l15) * DKc + kk * 32 + quad * 8];
#pragma unroll
        for (int mj = 0; mj < 4; ++mj)
#pragma unroll
            for (int ni = 0; ni < 4; ++ni) {
                f4 s = (f4)0.f;
                s = __builtin_amdgcn_mfma_f32_16x16x32_bf16(aK[mj][0], bQ[ni][0], s, 0, 0, 0);
                s = __builtin_amdgcn_mfma_f32_16x16x32_bf16(aK[mj][1], bQ[ni][1], s, 0, 0, 0);
#pragma unroll
                for (int r = 0; r < 4; ++r)
                    lsum[mj][r] += exp2f(s[r] * K2);
            }
    }
#pragma unroll
    for (int mj = 0; mj < 4; ++mj)
#pragma unroll
        for (int r = 0; r < 4; ++r) {
            float v = lsum[mj][r];
            v += __shfl_xor(v, 1); v += __shfl_xor(v, 2);
            v += __shfl_xor(v, 4); v += __shfl_xor(v, 8);
            if (l15 == 0)
                spart[((size_t)blockIdx.y * Bc * Hc + bh) * Nc + j0 + mj * 16 + quad * 4 + r] = v;
        }
}

// lcoef[g] = -log2( sum_splits spart[s][g] )
__global__ __launch_bounds__(256) void rcp_kernel(
    const float* __restrict__ spart, float* __restrict__ lcoef)
{
    int g = blockIdx.x * 256 + threadIdx.x;
    float s = 0.f;
#pragma unroll
    for (int p = 0; p < NSPLIT_S; ++p) s += spart[(size_t)p * BHN + g];
    lcoef[g] = -log2f(s);
}

// ---------------------------------------------------------------------------
// Kernel 3: partial PV over a j-chunk. Wave tile 64i x 64j.
// K/V staged once/block-iter via global_load_lds into XOR-swizzled LDS
// (granule swizzle c' = c ^ (row&7) -> all ds accesses bank-uniform).
// S^T via MFMA (A=K, B=Q-resident) -> P = 2^(s*K2 + lcoef) packed via v_perm
// (trunc) -> b64 writes to per-wave swizzled P -> b128 reads as A-op -> PV.
// grid (Nc/256, NSPLIT_A, B*H), block 256 (4 waves), 2 blocks/CU.
// ---------------------------------------------------------------------------
__global__ __launch_bounds__(256, 2) void apply_kernel(
    const ushort_t* __restrict__ q, const ushort_t* __restrict__ k,
    const ushort_t* __restrict__ vT, const float* __restrict__ lcoef,
    ushort_t* __restrict__ part0, ushort_t* __restrict__ part1)
{
    __shared__ __align__(16) ushort_t Ks[64 * 64];      // 8 KB swizzled
    __shared__ __align__(16) ushort_t Vs[64 * 64];      // 8 KB swizzled
    __shared__ __align__(16) ushort_t Ps[4][64 * 64];   // 32 KB per-wave swizzled
    const int tid = threadIdx.x;
    const int wave = tid >> 6, lane = tid & 63, quad = lane >> 4, l15 = lane & 15;
    const int bh = blockIdx.z, b = bh >> 3, h = bh & 7;
    const int i0 = blockIdx.x * 256 + wave * 64;
    const int jbase = blockIdx.y * (Nc / NSPLIT_A);
    const ushort_t* Q  = q  + ((size_t)bh * Nc + i0) * DKc;
    const ushort_t* Kb = k  + (size_t)bh * Nc * DKc;
    const ushort_t* Vb = vT + (size_t)bh * DKc * Nc;
    const float*   lcf = lcoef + (size_t)bh * Nc;
    ushort_t* Pw = Ps[wave];
    const int sw = l15 & 7;

    // Q B-frags resident (n=i, k=d)
    sh8 bQ[4][2];
#pragma unroll
    for (int ni = 0; ni < 4; ++ni)
#pragma unroll
        for (int kk = 0; kk < 2; ++kk)
            bQ[ni][kk] = *(const sh8*)&Q[(size_t)(ni * 16 + l15) * DKc + kk * 32 + quad * 8];

    f4 acc[4][4];
#pragma unroll
    for (int i = 0; i < 4; ++i)
#pragma unroll
        for (int j = 0; j < 4; ++j) acc[i][j] = (f4)0.f;

    // staging: granule g = wave*128 + c*64 + lane; row = g>>3, col = (g&7)^(row&7)
    int koff[2], voff[2], ldsb[2];
#pragma unroll
    for (int c = 0; c < 2; ++c) {
        int g = wave * 128 + c * 64 + lane;
        int r = g >> 3, cc = (g & 7) ^ (r & 7);
        koff[c] = r * DKc + cc * 8;       // K: row = j-local (row stride 64 elem)
        voff[c] = r * Nc + cc * 8;        // V^T: row = d     (row stride Nc elem)
        ldsb[c] = (wave * 128 + c * 64) * 8;  // wave-uniform LDS elem base
    }

    for (int jt = 0; jt < Nc / NSPLIT_A; jt += 64) {
        const int j0 = jbase + jt;
#pragma unroll
        for (int c = 0; c < 2; ++c) {
            gl_lds16(Kb + (size_t)j0 * DKc + koff[c], Ks + ldsb[c]);
            gl_lds16(Vb + (size_t)voff[c] + j0,       Vs + ldsb[c]);
        }
        __syncthreads();   // drains vmcnt (global_load_lds) + barrier

        // K A-frags (m=j, k=d) from swizzled LDS
        sh8 aK[4][2];
#pragma unroll
        for (int mj = 0; mj < 4; ++mj)
#pragma unroll
            for (int kk = 0; kk < 2; ++kk)
                aK[mj][kk] = *(const sh8*)&Ks[(mj * 16 + l15) * 64 + (((kk * 4 + quad) ^ sw)) * 8];
        float4 lc[4];
#pragma unroll
        for (int mj = 0; mj < 4; ++mj)
            lc[mj] = *(const float4*)&lcf[j0 + mj * 16 + quad * 4];

        // S^T + exp2 + packed P write
#pragma unroll
        for (int ni = 0; ni < 4; ++ni) {
            const int prow = ni * 16 + l15;
#pragma unroll
            for (int mj = 0; mj < 4; ++mj) {
                f4 s = (f4)0.f;
                s = __builtin_amdgcn_mfma_f32_16x16x32_bf16(aK[mj][0], bQ[ni][0], s, 0, 0, 0);
                s = __builtin_amdgcn_mfma_f32_16x16x32_bf16(aK[mj][1], bQ[ni][1], s, 0, 0, 0);
                unsigned e0 = fbits(exp2f(fmaf(s[0], K2, lc[mj].x)));
                unsigned e1 = fbits(exp2f(fmaf(s[1], K2, lc[mj].y)));
                unsigned e2 = fbits(exp2f(fmaf(s[2], K2, lc[mj].z)));
                unsigned e3 = fbits(exp2f(fmaf(s[3], K2, lc[mj].w)));
                uint2 pk;
                pk.x = __builtin_amdgcn_perm(e1, e0, 0x07060302u);  // [bf(e0),bf(e1)]
                pk.y = __builtin_amdgcn_perm(e3, e2, 0x07060302u);
                const int cg = (mj * 2 + (quad >> 1)) ^ sw;
                *(uint2*)&Pw[prow * 64 + cg * 8 + (quad & 1) * 4] = pk;
            }
        }

        // PV: A = P (m=i, k=j), B = V^T (n=d, k=j), both swizzled
#pragma unroll
        for (int kk = 0; kk < 2; ++kk) {
            const int cgk = ((kk * 4 + quad) ^ sw) * 8;
            sh8 aP[4], bV[4];
#pragma unroll
            for (int mi = 0; mi < 4; ++mi)
                aP[mi] = *(const sh8*)&Pw[(mi * 16 + l15) * 64 + cgk];
#pragma unroll
            for (int nd = 0; nd < 4; ++nd)
                bV[nd] = *(const sh8*)&Vs[(nd * 16 + l15) * 64 + cgk];
#pragma unroll
            for (int mi = 0; mi < 4; ++mi)
#pragma unroll
                for (int nd = 0; nd < 4; ++nd)
                    acc[mi][nd] = __builtin_amdgcn_mfma_f32_16x16x32_bf16(
                        aP[mi], bV[nd], acc[mi][nd], 0, 0, 0);
        }
        __syncthreads();   // protect Ks/Vs before next stage
    }

    ushort_t* part = blockIdx.y ? part1 : part0;
    ushort_t* dst = part + ((size_t)b * Nc + i0) * Cc + h * DKc;
#pragma unroll
    for (int mi = 0; mi < 4; ++mi)
#pragma unroll
        for (int nd = 0; nd < 4; ++nd)
#pragma unroll
            for (int r = 0; r < 4; ++r)
                dst[(size_t)(mi * 16 + quad * 4 + r) * Cc + nd * 16 + l15] =
                    f2bf(acc[mi][nd][r]);
}

// res (== part1 in-place) = bf16( fp32(part0) + fp32(part1) )
__global__ __launch_bounds__(256) void reduce_kernel(
    const ushort_t* __restrict__ p0, ushort_t* __restrict__ p1res)
{
    int i = blockIdx.x * 256 + threadIdx.x;
    us4 a = ((const us4*)p0)[i];
    us4 b = ((const us4*)p1res)[i];
    us4 o;
#pragma unroll
    for (int j = 0; j < 4; ++j)
        o[j] = f2bf(bf2f(a[j]) + bf2f(b[j]));
    ((us4*)p1res)[i] = o;
}

// ---------------------------------------------------------------------------
// Kernel 4: out[b,co,n] = res @ Wo^T + bo + x (unchanged; passed)
// ---------------------------------------------------------------------------
__global__ __launch_bounds__(256) void out_kernel(
    const ushort_t* __restrict__ res, const ushort_t* __restrict__ Wob,
    const float* __restrict__ bo, const float* __restrict__ x,
    float* __restrict__ out)
{
    const int tid = threadIdx.x;
    const int wave = tid >> 6, lane = tid & 63, quad = lane >> 4, l15 = lane & 15;
    const int m0  = blockIdx.x * 128 + (wave & 1) * 64;
    const int co0 = blockIdx.y * 128 + (wave >> 1) * 64;
    const ushort_t* A  = res + (size_t)m0 * Cc;
    const ushort_t* Bw = Wob + (size_t)co0 * Cc;

    f4 acc[4][4];
#pragma unroll
    for (int i = 0; i < 4; ++i)
#pragma unroll
        for (int j = 0; j < 4; ++j) acc[i][j] = (f4)0.f;

    for (int kk = 0; kk < Cc; kk += 32) {
        sh8 a[4], bb[4];
#pragma unroll
        for (int mi = 0; mi < 4; ++mi)
            a[mi] = *(const sh8*)&A[(size_t)(mi * 16 + l15) * Cc + kk + quad * 8];
#pragma unroll
        for (int ni = 0; ni < 4; ++ni)
            bb[ni] = *(const sh8*)&Bw[(size_t)(ni * 16 + l15) * Cc + kk + quad * 8];
#pragma unroll
        for (int mi = 0; mi < 4; ++mi)
#pragma unroll
            for (int ni = 0; ni < 4; ++ni)
                acc[mi][ni] = __builtin_amdgcn_mfma_f32_16x16x32_bf16(
                    a[mi], bb[ni], acc[mi][ni], 0, 0, 0);
    }

    const int b = m0 >> 11;
    const int n_base = m0 & 2047;
#pragma unroll
    for (int ni = 0; ni < 4; ++ni) {
        const int co = co0 + ni * 16 + l15;
        const float bias = bo[co];
#pragma unroll
        for (int mi = 0; mi < 4; ++mi) {
            const int n = n_base + mi * 16 + quad * 4;
            const size_t idx = ((size_t)b * Cc + co) * Nc + n;
            float4 xr = *(const float4*)&x[idx];
            float4 o;
            o.x = acc[mi][ni][0] + bias + xr.x;
            o.y = acc[mi][ni][1] + bias + xr.y;
            o.z = acc[mi][ni][2] + bias + xr.z;
            o.w = acc[mi][ni][3] + bias + xr.w;
            *(float4*)&out[idx] = o;
        }
    }
}

// ---------------------------------------------------------------------------
extern "C" void kernel_launch(void* const* d_in, const int* in_sizes, int n_in,
                              void* d_out, int out_size, void* d_ws, size_t ws_size,
                              hipStream_t stream)
{
    const float* x  = (const float*)d_in[0];
    const float* Wp = (const float*)d_in[1];
    const float* bp = (const float*)d_in[2];
    const float* Wo = (const float*)d_in[3];
    const float* bo = (const float*)d_in[4];
    float* out = (float*)d_out;

    float* lcoef = (float*)d_ws;                              // BHN
    float* spart = lcoef + BHN;                               // NSPLIT_S * BHN
    ushort_t* wsb = (ushort_t*)(spart + (size_t)NSPLIT_S * BHN);
    const size_t nE = (size_t)Bc * Nc * Cc;                   // 4,194,304
    ushort_t* xt  = wsb;                 // also part0 (dead after qkv)
    ushort_t* Wpb = xt  + nE;
    ushort_t* Wob = Wpb + (size_t)O3c * Cc;
    ushort_t* qw  = Wob + (size_t)Cc * Cc;
    ushort_t* kw  = qw + nE;
    ushort_t* vT  = kw + nE;
    ushort_t* res = vT + nE;             // also part1

    xpose_kernel<<<dim3(Nc / 32, Cc / 32, Bc), 256, 0, stream>>>(x, xt);
    cvt_kernel<<<dim3((O3c * Cc / 4 + 255) / 256), 256, 0, stream>>>(Wp, Wpb, O3c * Cc / 4);
    cvt_kernel<<<dim3((Cc * Cc / 4 + 255) / 256), 256, 0, stream>>>(Wo, Wob, Cc * Cc / 4);
    qkv_kernel<<<dim3(O3c / 128, Nc / 128, Bc), 256, 0, stream>>>(xt, Wpb, bp, qw, kw, vT);
    stats_kernel<<<dim3(Nc / 256, NSPLIT_S, Bc * Hc), 256, 0, stream>>>(qw, kw, spart);
    rcp_kernel<<<dim3(BHN / 256), 256, 0, stream>>>(spart, lcoef);
    apply_kernel<<<dim3(Nc / 256, NSPLIT_A, Bc * Hc), 256, 0, stream>>>(qw, kw, vT, lcoef, xt, res);
    reduce_kernel<<<dim3((int)(nE / 4 / 256)), 256, 0, stream>>>(xt, res);
    out_kernel<<<dim3(Bc * Nc / 128, Cc / 128), 256, 0, stream>>>(res, Wob, bo, x, out);
}

// Round 5
// 272.607 us; speedup vs baseline: 1.8588x; 1.0337x over previous
//
#include <hip/hip_runtime.h>
#include <cstddef>

typedef unsigned short ushort_t;
typedef __attribute__((ext_vector_type(8))) short sh8;   // 8 x bf16 bits = 4 VGPRs
typedef __attribute__((ext_vector_type(4))) float f4;    // MFMA 16x16x32 C/D
typedef __attribute__((ext_vector_type(4))) unsigned short us4;

static constexpr int Bc = 4, Cc = 512, Nc = 2048, Hc = 8, DKc = 64, O3c = 1536;
static constexpr int BHN = Bc * Hc * Nc;               // 65536
static constexpr int NSPLIT_S = 2;                     // stats i-split
static constexpr float K2 = 0.125f * 1.44269504089f;   // scale * log2(e), folded into q

__device__ __forceinline__ unsigned short f2bf(float f) {
    union { float f; unsigned u; } v; v.f = f;
    unsigned r = v.u + 0x7FFFu + ((v.u >> 16) & 1u);  // RNE
    return (unsigned short)(r >> 16);
}
__device__ __forceinline__ float bf2f(unsigned short b) {
    union { unsigned u; float f; } v; v.u = ((unsigned)b) << 16;
    return v.f;
}
__device__ __forceinline__ unsigned fbits(float f) {
    union { float f; unsigned u; } v; v.f = f; return v.u;
}
__device__ __forceinline__ void gl_lds16(const ushort_t* g, ushort_t* l) {
    __builtin_amdgcn_global_load_lds(
        (const __attribute__((address_space(1))) unsigned int*)g,
        (__attribute__((address_space(3))) unsigned int*)l, 16, 0, 0);
}

// ---------------------------------------------------------------------------
// Prep A: x[b,c,n] fp32 -> xt[b,n,c] bf16
// ---------------------------------------------------------------------------
__global__ __launch_bounds__(256) void xpose_kernel(
    const float* __restrict__ x, ushort_t* __restrict__ xt)
{
    __shared__ float t[32][33];
    const int b = blockIdx.z, n0 = blockIdx.x * 32, c0 = blockIdx.y * 32;
    const int tx = threadIdx.x & 31, ty = threadIdx.x >> 5;
    const float* xb = x + (size_t)b * Cc * Nc;
#pragma unroll
    for (int r = 0; r < 4; ++r)
        t[ty + r * 8][tx] = xb[(size_t)(c0 + ty + r * 8) * Nc + n0 + tx];
    __syncthreads();
    ushort_t* xtb = xt + (size_t)b * Nc * Cc;
#pragma unroll
    for (int r = 0; r < 4; ++r)
        xtb[(size_t)(n0 + ty + r * 8) * Cc + c0 + tx] = f2bf(t[tx][ty + r * 8]);
}

// ---------------------------------------------------------------------------
// Prep B: fp32 -> bf16 bulk convert
// ---------------------------------------------------------------------------
__global__ __launch_bounds__(256) void cvt_kernel(
    const float* __restrict__ s, ushort_t* __restrict__ d, int n4)
{
    int i = blockIdx.x * 256 + threadIdx.x;
    if (i < n4) {
        float4 v = ((const float4*)s)[i];
        us4 o = { f2bf(v.x), f2bf(v.y), f2bf(v.z), f2bf(v.w) };
        ((us4*)d)[i] = o;
    }
}

// ---------------------------------------------------------------------------
// Kernel 1: qkv projection. q rows pre-scaled by K2 (so S = q.k is already
// in log2-domain units; exp becomes a bare v_exp_f32 downstream).
// ---------------------------------------------------------------------------
__global__ __launch_bounds__(256) void qkv_kernel(
    const ushort_t* __restrict__ xt, const ushort_t* __restrict__ Wpb,
    const float* __restrict__ bp,
    ushort_t* __restrict__ q, ushort_t* __restrict__ k, ushort_t* __restrict__ vT)
{
    const int tid = threadIdx.x;
    const int wave = tid >> 6, lane = tid & 63, quad = lane >> 4, l15 = lane & 15;
    const int b = blockIdx.z;
    const int m0 = blockIdx.y * 128 + (wave & 1) * 64;
    const int o0 = blockIdx.x * 128 + (wave >> 1) * 64;
    const ushort_t* A  = xt  + ((size_t)b * Nc + m0) * Cc;
    const ushort_t* Bp = Wpb + (size_t)o0 * Cc;

    f4 acc[4][4];
#pragma unroll
    for (int i = 0; i < 4; ++i)
#pragma unroll
        for (int j = 0; j < 4; ++j) acc[i][j] = (f4)0.f;

    for (int kk = 0; kk < Cc; kk += 32) {
        sh8 a[4], bb[4];
#pragma unroll
        for (int mi = 0; mi < 4; ++mi)
            a[mi] = *(const sh8*)&A[(size_t)(mi * 16 + l15) * Cc + kk + quad * 8];
#pragma unroll
        for (int ni = 0; ni < 4; ++ni)
            bb[ni] = *(const sh8*)&Bp[(size_t)(ni * 16 + l15) * Cc + kk + quad * 8];
#pragma unroll
        for (int mi = 0; mi < 4; ++mi)
#pragma unroll
            for (int ni = 0; ni < 4; ++ni)
                acc[mi][ni] = __builtin_amdgcn_mfma_f32_16x16x32_bf16(
                    a[mi], bb[ni], acc[mi][ni], 0, 0, 0);
    }

    const int f  = (o0 >> 6) % 3;
    const int h  = o0 / 192;
    const int bh = b * Hc + h;
    const float qscale = (f == 0) ? K2 : 1.0f;
#pragma unroll
    for (int ni = 0; ni < 4; ++ni) {
        const int o = o0 + ni * 16 + l15;
        const int d = o & 63;
        const float bias = bp[o];
        if (f == 2) {
            ushort_t* dst = vT + ((size_t)bh * DKc + d) * Nc + m0;
#pragma unroll
            for (int mi = 0; mi < 4; ++mi) {
                us4 pk = { f2bf(acc[mi][ni][0] + bias), f2bf(acc[mi][ni][1] + bias),
                           f2bf(acc[mi][ni][2] + bias), f2bf(acc[mi][ni][3] + bias) };
                *(us4*)&dst[mi * 16 + quad * 4] = pk;
            }
        } else {
            ushort_t* dst = (f == 0 ? q : k) + ((size_t)bh * Nc + m0) * DKc + d;
#pragma unroll
            for (int mi = 0; mi < 4; ++mi)
#pragma unroll
                for (int r = 0; r < 4; ++r)
                    dst[(size_t)(mi * 16 + quad * 4 + r) * DKc] =
                        f2bf((acc[mi][ni][r] + bias) * qscale);
        }
    }
}

// ---------------------------------------------------------------------------
// Kernel 2: partial column sums. spart[split][bh][j] = sum_{i chunk} 2^s.
// 1D grid 512, XCD-swizzled: id = jb*64 + bh*2 + js.
// ---------------------------------------------------------------------------
__global__ __launch_bounds__(256, 2) void stats_kernel(
    const ushort_t* __restrict__ q, const ushort_t* __restrict__ k,
    float* __restrict__ spart)
{
    const int tid = threadIdx.x;
    const int wave = tid >> 6, lane = tid & 63, quad = lane >> 4, l15 = lane & 15;
    const int id = blockIdx.x;
    const int jb = id >> 6;
    const int bh = (id & 63) >> 1;
    const int js = id & 1;
    const int j0 = jb * 256 + wave * 64;
    const int ibase = js * (Nc / NSPLIT_S);
    const ushort_t* K = k + ((size_t)bh * Nc + j0) * DKc;
    const ushort_t* Q = q + (size_t)bh * Nc * DKc;

    sh8 aK[4][2];
#pragma unroll
    for (int mj = 0; mj < 4; ++mj)
#pragma unroll
        for (int kk = 0; kk < 2; ++kk)
            aK[mj][kk] = *(const sh8*)&K[(size_t)(mj * 16 + l15) * DKc + kk * 32 + quad * 8];

    float lsum[4][4] = {};
    for (int it = 0; it < Nc / NSPLIT_S; it += 64) {
        const int i0 = ibase + it;
        sh8 bQ[4][2];
#pragma unroll
        for (int ni = 0; ni < 4; ++ni)
#pragma unroll
            for (int kk = 0; kk < 2; ++kk)
                bQ[ni][kk] = *(const sh8*)&Q[(size_t)(i0 + ni * 16 + l15) * DKc + kk * 32 + quad * 8];
#pragma unroll
        for (int mj = 0; mj < 4; ++mj)
#pragma unroll
            for (int ni = 0; ni < 4; ++ni) {
                f4 s = (f4)0.f;
                s = __builtin_amdgcn_mfma_f32_16x16x32_bf16(aK[mj][0], bQ[ni][0], s, 0, 0, 0);
                s = __builtin_amdgcn_mfma_f32_16x16x32_bf16(aK[mj][1], bQ[ni][1], s, 0, 0, 0);
#pragma unroll
                for (int r = 0; r < 4; ++r)
                    lsum[mj][r] += exp2f(s[r]);
            }
    }
#pragma unroll
    for (int mj = 0; mj < 4; ++mj)
#pragma unroll
        for (int r = 0; r < 4; ++r) {
            float v = lsum[mj][r];
            v += __shfl_xor(v, 1); v += __shfl_xor(v, 2);
            v += __shfl_xor(v, 4); v += __shfl_xor(v, 8);
            if (l15 == 0)
                spart[((size_t)js * Bc * Hc + bh) * Nc + j0 + mj * 16 + quad * 4 + r] = v;
        }
}

// coef[g] = 1 / sum_splits spart[s][g]
__global__ __launch_bounds__(256) void rcp_kernel(
    const float* __restrict__ spart, float* __restrict__ coef)
{
    int g = blockIdx.x * 256 + threadIdx.x;
    float s = 0.f;
#pragma unroll
    for (int p = 0; p < NSPLIT_S; ++p) s += spart[(size_t)p * BHN + g];
    coef[g] = 1.0f / s;
}

// vT[bh,d,j] *= coef[bh,j]  (fold softmax denom into V once)
__global__ __launch_bounds__(256) void vscale_kernel(
    ushort_t* __restrict__ vT, const float* __restrict__ coef)
{
    int i = blockIdx.x * 256 + threadIdx.x;   // us4 index
    int f = i * 4;
    int row = f >> 11;                        // bh*64 + d
    int j = f & 2047;
    int bh = row >> 6;
    float4 c = *(const float4*)&coef[(size_t)bh * Nc + j];
    us4 v = ((us4*)vT)[i];
    us4 o = { f2bf(bf2f(v[0]) * c.x), f2bf(bf2f(v[1]) * c.y),
              f2bf(bf2f(v[2]) * c.z), f2bf(bf2f(v[3]) * c.w) };
    ((us4*)vT)[i] = o;
}

// ---------------------------------------------------------------------------
// Kernel 3: partial PV over a j-chunk. Wave tile 64i x (whole j chunk).
// 128-j LDS stages (K,V via global_load_lds, granule-XOR swizzle).
// P layout: half-granule XOR -> conflict-free b64 writes AND b64 reads.
// 1D grid 512, XCD-swizzled: id = ib*64 + bh*2 + js.
// ---------------------------------------------------------------------------
__global__ __launch_bounds__(256, 2) void apply_kernel(
    const ushort_t* __restrict__ q, const ushort_t* __restrict__ k,
    const ushort_t* __restrict__ vT,
    ushort_t* __restrict__ part0, ushort_t* __restrict__ part1)
{
    __shared__ __align__(16) ushort_t Ks[128 * 64];     // 16 KB
    __shared__ __align__(16) ushort_t Vs[64 * 128];     // 16 KB
    __shared__ __align__(16) ushort_t Ps[4][64 * 64];   // 32 KB per-wave
    const int tid = threadIdx.x;
    const int wave = tid >> 6, lane = tid & 63, quad = lane >> 4, l15 = lane & 15;
    const int id = blockIdx.x;
    const int ibk = id >> 6;
    const int bh = (id & 63) >> 1;
    const int js = id & 1;
    const int b = bh >> 3, h = bh & 7;
    const int i0 = ibk * 256 + wave * 64;
    const int jbase = js * (Nc / 2);
    const ushort_t* Q  = q  + ((size_t)bh * Nc + i0) * DKc;
    const ushort_t* Kb = k  + (size_t)bh * Nc * DKc;
    const ushort_t* Vb = vT + (size_t)bh * DKc * Nc;
    ushort_t* Pw = Ps[wave];
    const int sw = l15 & 7;
    const int hb = (l15 >> 3) & 1;        // high-half swizzle bit

    // Q B-frags resident (n=i, k=d); q already scaled by K2
    sh8 bQ[4][2];
#pragma unroll
    for (int ni = 0; ni < 4; ++ni)
#pragma unroll
        for (int kk = 0; kk < 2; ++kk)
            bQ[ni][kk] = *(const sh8*)&Q[(size_t)(ni * 16 + l15) * DKc + kk * 32 + quad * 8];

    f4 acc[4][4];
#pragma unroll
    for (int i = 0; i < 4; ++i)
#pragma unroll
        for (int j = 0; j < 4; ++j) acc[i][j] = (f4)0.f;

    // staging offsets: slot g holds natural granule (slot ^ rowkey)
    int koff[4], voff[4], lbase[4];
#pragma unroll
    for (int c = 0; c < 4; ++c) {
        int g = c * 256 + tid;
        int rk = g >> 3, ck = (g & 7) ^ (rk & 7);
        koff[c] = rk * DKc + ck * 8;
        int rv = g >> 4, cs = g & 15, cn = (cs & 8) | ((cs & 7) ^ (rv & 7));
        voff[c] = rv * Nc + cn * 8;
        lbase[c] = (c * 256 + wave * 64) * 8;
    }

    for (int st = 0; st < 8; ++st) {
        const int j0 = jbase + st * 128;
#pragma unroll
        for (int c = 0; c < 4; ++c) {
            gl_lds16(Kb + (size_t)j0 * DKc + koff[c], Ks + lbase[c]);
            gl_lds16(Vb + voff[c] + j0,               Vs + lbase[c]);
        }
        __syncthreads();

#pragma unroll
        for (int jj = 0; jj < 128; jj += 64) {
            // K A-frags (m=j, k=d)
            sh8 aK[4][2];
#pragma unroll
            for (int mj = 0; mj < 4; ++mj)
#pragma unroll
                for (int kk = 0; kk < 2; ++kk)
                    aK[mj][kk] = *(const sh8*)&Ks[(jj + mj * 16 + l15) * 64 +
                                                  (((kk * 4 + quad) ^ sw) << 3)];
            // S^T + exp + conflict-free packed P write
#pragma unroll
            for (int ni = 0; ni < 4; ++ni) {
                const int prow = ni * 16 + l15;
#pragma unroll
                for (int mj = 0; mj < 4; ++mj) {
                    f4 s = (f4)0.f;
                    s = __builtin_amdgcn_mfma_f32_16x16x32_bf16(aK[mj][0], bQ[ni][0], s, 0, 0, 0);
                    s = __builtin_amdgcn_mfma_f32_16x16x32_bf16(aK[mj][1], bQ[ni][1], s, 0, 0, 0);
                    unsigned e0 = fbits(exp2f(s[0]));
                    unsigned e1 = fbits(exp2f(s[1]));
                    unsigned e2 = fbits(exp2f(s[2]));
                    unsigned e3 = fbits(exp2f(s[3]));
                    uint2 pk;
                    pk.x = __builtin_amdgcn_perm(e1, e0, 0x07060302u);
                    pk.y = __builtin_amdgcn_perm(e3, e2, 0x07060302u);
                    const int off = prow * 64 + ((((mj * 2 + (quad >> 1)) ^ sw)) << 3)
                                  + (((quad & 1) ^ hb) << 2);
                    *(uint2*)&Pw[off] = pk;
                }
            }
            // PV: A = P via 2x b64 (halves re-ordered by hb), B = Vs b128
#pragma unroll
            for (int kk = 0; kk < 2; ++kk) {
                const int cgk = (((kk * 4 + quad) ^ sw)) << 3;
                const int h0 = hb << 2, h1 = 4 - h0;
                sh8 aP[4], bV[4];
#pragma unroll
                for (int mi = 0; mi < 4; ++mi) {
                    union { sh8 s8; uint2 u[2]; } t;
                    const int rb = (mi * 16 + l15) * 64 + cgk;
                    t.u[0] = *(const uint2*)&Pw[rb + h0];   // j lo-half
                    t.u[1] = *(const uint2*)&Pw[rb + h1];   // j hi-half
                    aP[mi] = t.s8;
                }
                const int gnat = (jj >> 3) + kk * 4 + quad;
                const int vcg = ((gnat & 8) | ((gnat & 7) ^ sw)) << 3;
#pragma unroll
                for (int nd = 0; nd < 4; ++nd)
                    bV[nd] = *(const sh8*)&Vs[(nd * 16 + l15) * 128 + vcg];
#pragma unroll
                for (int mi = 0; mi < 4; ++mi)
#pragma unroll
                    for (int nd = 0; nd < 4; ++nd)
                        acc[mi][nd] = __builtin_amdgcn_mfma_f32_16x16x32_bf16(
                            aP[mi], bV[nd], acc[mi][nd], 0, 0, 0);
            }
        }
        __syncthreads();
    }

    ushort_t* part = js ? part1 : part0;
    ushort_t* dst = part + ((size_t)b * Nc + i0) * Cc + h * DKc;
#pragma unroll
    for (int mi = 0; mi < 4; ++mi)
#pragma unroll
        for (int nd = 0; nd < 4; ++nd)
#pragma unroll
            for (int r = 0; r < 4; ++r)
                dst[(size_t)(mi * 16 + quad * 4 + r) * Cc + nd * 16 + l15] =
                    f2bf(acc[mi][nd][r]);
}

// res (== part1 in-place) = bf16( fp32(part0) + fp32(part1) )
__global__ __launch_bounds__(256) void reduce_kernel(
    const ushort_t* __restrict__ p0, ushort_t* __restrict__ p1res)
{
    int i = blockIdx.x * 256 + threadIdx.x;
    us4 a = ((const us4*)p0)[i];
    us4 b = ((const us4*)p1res)[i];
    us4 o;
#pragma unroll
    for (int j = 0; j < 4; ++j)
        o[j] = f2bf(bf2f(a[j]) + bf2f(b[j]));
    ((us4*)p1res)[i] = o;
}

// ---------------------------------------------------------------------------
// Kernel 4: out[b,co,n] = res @ Wo^T + bo + x
// ---------------------------------------------------------------------------
__global__ __launch_bounds__(256) void out_kernel(
    const ushort_t* __restrict__ res, const ushort_t* __restrict__ Wob,
    const float* __restrict__ bo, const float* __restrict__ x,
    float* __restrict__ out)
{
    const int tid = threadIdx.x;
    const int wave = tid >> 6, lane = tid & 63, quad = lane >> 4, l15 = lane & 15;
    const int m0  = blockIdx.x * 128 + (wave & 1) * 64;
    const int co0 = blockIdx.y * 128 + (wave >> 1) * 64;
    const ushort_t* A  = res + (size_t)m0 * Cc;
    const ushort_t* Bw = Wob + (size_t)co0 * Cc;

    f4 acc[4][4];
#pragma unroll
    for (int i = 0; i < 4; ++i)
#pragma unroll
        for (int j = 0; j < 4; ++j) acc[i][j] = (f4)0.f;

    for (int kk = 0; kk < Cc; kk += 32) {
        sh8 a[4], bb[4];
#pragma unroll
        for (int mi = 0; mi < 4; ++mi)
            a[mi] = *(const sh8*)&A[(size_t)(mi * 16 + l15) * Cc + kk + quad * 8];
#pragma unroll
        for (int ni = 0; ni < 4; ++ni)
            bb[ni] = *(const sh8*)&Bw[(size_t)(ni * 16 + l15) * Cc + kk + quad * 8];
#pragma unroll
        for (int mi = 0; mi < 4; ++mi)
#pragma unroll
            for (int ni = 0; ni < 4; ++ni)
                acc[mi][ni] = __builtin_amdgcn_mfma_f32_16x16x32_bf16(
                    a[mi], bb[ni], acc[mi][ni], 0, 0, 0);
    }

    const int b = m0 >> 11;
    const int n_base = m0 & 2047;
#pragma unroll
    for (int ni = 0; ni < 4; ++ni) {
        const int co = co0 + ni * 16 + l15;
        const float bias = bo[co];
#pragma unroll
        for (int mi = 0; mi < 4; ++mi) {
            const int n = n_base + mi * 16 + quad * 4;
            const size_t idx = ((size_t)b * Cc + co) * Nc + n;
            float4 xr = *(const float4*)&x[idx];
            float4 o;
            o.x = acc[mi][ni][0] + bias + xr.x;
            o.y = acc[mi][ni][1] + bias + xr.y;
            o.z = acc[mi][ni][2] + bias + xr.z;
            o.w = acc[mi][ni][3] + bias + xr.w;
            *(float4*)&out[idx] = o;
        }
    }
}

// ---------------------------------------------------------------------------
extern "C" void kernel_launch(void* const* d_in, const int* in_sizes, int n_in,
                              void* d_out, int out_size, void* d_ws, size_t ws_size,
                              hipStream_t stream)
{
    const float* x  = (const float*)d_in[0];
    const float* Wp = (const float*)d_in[1];
    const float* bp = (const float*)d_in[2];
    const float* Wo = (const float*)d_in[3];
    const float* bo = (const float*)d_in[4];
    float* out = (float*)d_out;

    float* coef  = (float*)d_ws;                              // BHN
    float* spart = coef + BHN;                                // NSPLIT_S * BHN
    ushort_t* wsb = (ushort_t*)(spart + (size_t)NSPLIT_S * BHN);
    const size_t nE = (size_t)Bc * Nc * Cc;                   // 4,194,304
    ushort_t* xt  = wsb;                 // also part0 (dead after qkv)
    ushort_t* Wpb = xt  + nE;
    ushort_t* Wob = Wpb + (size_t)O3c * Cc;
    ushort_t* qw  = Wob + (size_t)Cc * Cc;
    ushort_t* kw  = qw + nE;
    ushort_t* vT  = kw + nE;
    ushort_t* res = vT + nE;             // also part1

    xpose_kernel<<<dim3(Nc / 32, Cc / 32, Bc), 256, 0, stream>>>(x, xt);
    cvt_kernel<<<dim3((O3c * Cc / 4 + 255) / 256), 256, 0, stream>>>(Wp, Wpb, O3c * Cc / 4);
    cvt_kernel<<<dim3((Cc * Cc / 4 + 255) / 256), 256, 0, stream>>>(Wo, Wob, Cc * Cc / 4);
    qkv_kernel<<<dim3(O3c / 128, Nc / 128, Bc), 256, 0, stream>>>(xt, Wpb, bp, qw, kw, vT);
    stats_kernel<<<dim3(512), 256, 0, stream>>>(qw, kw, spart);
    rcp_kernel<<<dim3(BHN / 256), 256, 0, stream>>>(spart, coef);
    vscale_kernel<<<dim3((int)(nE / 4 / 256)), 256, 0, stream>>>(vT, coef);
    apply_kernel<<<dim3(512), 256, 0, stream>>>(qw, kw, vT, xt, res);
    reduce_kernel<<<dim3((int)(nE / 4 / 256)), 256, 0, stream>>>(xt, res);
    out_kernel<<<dim3(Bc * Nc / 128, Cc / 128), 256, 0, stream>>>(res, Wob, bo, x, out);
}

// Round 6
// 256.212 us; speedup vs baseline: 1.9778x; 1.0640x over previous
//
#include <hip/hip_runtime.h>
#include <cstddef>

typedef unsigned short ushort_t;
typedef __attribute__((ext_vector_type(8))) short sh8;   // 8 x bf16 bits = 4 VGPRs
typedef __attribute__((ext_vector_type(4))) float f4;    // MFMA 16x16x32 C/D
typedef __attribute__((ext_vector_type(4))) unsigned short us4;

static constexpr int Bc = 4, Cc = 512, Nc = 2048, Hc = 8, DKc = 64, O3c = 1536;
static constexpr int BHN = Bc * Hc * Nc;               // 65536
static constexpr int NSPLIT_S = 2;                     // stats i-split
static constexpr float K2 = 0.125f * 1.44269504089f;   // scale * log2(e), folded into q

__device__ __forceinline__ unsigned short f2bf(float f) {
    union { float f; unsigned u; } v; v.f = f;
    unsigned r = v.u + 0x7FFFu + ((v.u >> 16) & 1u);  // RNE
    return (unsigned short)(r >> 16);
}
__device__ __forceinline__ float bf2f(unsigned short b) {
    union { unsigned u; float f; } v; v.u = ((unsigned)b) << 16;
    return v.f;
}
__device__ __forceinline__ unsigned fbits(float f) {
    union { float f; unsigned u; } v; v.f = f; return v.u;
}
__device__ __forceinline__ void gl_lds16(const ushort_t* g, ushort_t* l) {
    __builtin_amdgcn_global_load_lds(
        (const __attribute__((address_space(1))) unsigned int*)g,
        (__attribute__((address_space(3))) unsigned int*)l, 16, 0, 0);
}

// ---------------------------------------------------------------------------
// Prep A: x[b,c,n] fp32 -> xt[b,n,c] bf16
// ---------------------------------------------------------------------------
__global__ __launch_bounds__(256) void xpose_kernel(
    const float* __restrict__ x, ushort_t* __restrict__ xt)
{
    __shared__ float t[32][33];
    const int b = blockIdx.z, n0 = blockIdx.x * 32, c0 = blockIdx.y * 32;
    const int tx = threadIdx.x & 31, ty = threadIdx.x >> 5;
    const float* xb = x + (size_t)b * Cc * Nc;
#pragma unroll
    for (int r = 0; r < 4; ++r)
        t[ty + r * 8][tx] = xb[(size_t)(c0 + ty + r * 8) * Nc + n0 + tx];
    __syncthreads();
    ushort_t* xtb = xt + (size_t)b * Nc * Cc;
#pragma unroll
    for (int r = 0; r < 4; ++r)
        xtb[(size_t)(n0 + ty + r * 8) * Cc + c0 + tx] = f2bf(t[tx][ty + r * 8]);
}

// ---------------------------------------------------------------------------
// Prep B: fp32 -> bf16 bulk convert
// ---------------------------------------------------------------------------
__global__ __launch_bounds__(256) void cvt_kernel(
    const float* __restrict__ s, ushort_t* __restrict__ d, int n4)
{
    int i = blockIdx.x * 256 + threadIdx.x;
    if (i < n4) {
        float4 v = ((const float4*)s)[i];
        us4 o = { f2bf(v.x), f2bf(v.y), f2bf(v.z), f2bf(v.w) };
        ((us4*)d)[i] = o;
    }
}

// ---------------------------------------------------------------------------
// Kernel 1: qkv projection. q rows pre-scaled by K2.
// f=2 (v) waves: C[token][o] (A=xt,B=Wp) -> vT [d][n] us4 stores.
// f=0/1 (q,k) waves: C[o][token] (A=Wp,B=xt) -> q/k [n][d] us4 stores of
//   4 consecutive d — 16 lines/inst instead of 64 (kills the 64-way
//   write-transaction scatter that made R5's qkv 66 us).
// ---------------------------------------------------------------------------
__global__ __launch_bounds__(256) void qkv_kernel(
    const ushort_t* __restrict__ xt, const ushort_t* __restrict__ Wpb,
    const float* __restrict__ bp,
    ushort_t* __restrict__ q, ushort_t* __restrict__ k, ushort_t* __restrict__ vT)
{
    const int tid = threadIdx.x;
    const int wave = tid >> 6, lane = tid & 63, quad = lane >> 4, l15 = lane & 15;
    const int b = blockIdx.z;
    const int m0 = blockIdx.y * 128 + (wave & 1) * 64;   // token base
    const int o0 = blockIdx.x * 128 + (wave >> 1) * 64;  // qkv feature base
    const ushort_t* A  = xt  + ((size_t)b * Nc + m0) * Cc;
    const ushort_t* Bp = Wpb + (size_t)o0 * Cc;

    const int f  = (o0 >> 6) % 3;   // wave-uniform
    const int h  = o0 / 192;
    const int bh = b * Hc + h;

    f4 acc[4][4];
#pragma unroll
    for (int i = 0; i < 4; ++i)
#pragma unroll
        for (int j = 0; j < 4; ++j) acc[i][j] = (f4)0.f;

    if (f == 2) {
        // C[token][o]
        for (int kk = 0; kk < Cc; kk += 32) {
            sh8 a[4], bb[4];
#pragma unroll
            for (int mi = 0; mi < 4; ++mi)
                a[mi] = *(const sh8*)&A[(size_t)(mi * 16 + l15) * Cc + kk + quad * 8];
#pragma unroll
            for (int ni = 0; ni < 4; ++ni)
                bb[ni] = *(const sh8*)&Bp[(size_t)(ni * 16 + l15) * Cc + kk + quad * 8];
#pragma unroll
            for (int mi = 0; mi < 4; ++mi)
#pragma unroll
                for (int ni = 0; ni < 4; ++ni)
                    acc[mi][ni] = __builtin_amdgcn_mfma_f32_16x16x32_bf16(
                        a[mi], bb[ni], acc[mi][ni], 0, 0, 0);
        }
#pragma unroll
        for (int ni = 0; ni < 4; ++ni) {
            const int o = o0 + ni * 16 + l15;
            const int d = o & 63;
            const float bias = bp[o];
            ushort_t* dst = vT + ((size_t)bh * DKc + d) * Nc + m0;
#pragma unroll
            for (int mi = 0; mi < 4; ++mi) {
                us4 pk = { f2bf(acc[mi][ni][0] + bias), f2bf(acc[mi][ni][1] + bias),
                           f2bf(acc[mi][ni][2] + bias), f2bf(acc[mi][ni][3] + bias) };
                *(us4*)&dst[mi * 16 + quad * 4] = pk;
            }
        }
    } else {
        // C[o][token]: A = Wp rows, B = xt rows (same loads, swapped mfma)
        for (int kk = 0; kk < Cc; kk += 32) {
            sh8 a[4], bb[4];
#pragma unroll
            for (int mi = 0; mi < 4; ++mi)
                a[mi] = *(const sh8*)&A[(size_t)(mi * 16 + l15) * Cc + kk + quad * 8];
#pragma unroll
            for (int ni = 0; ni < 4; ++ni)
                bb[ni] = *(const sh8*)&Bp[(size_t)(ni * 16 + l15) * Cc + kk + quad * 8];
#pragma unroll
            for (int mo = 0; mo < 4; ++mo)
#pragma unroll
                for (int nt = 0; nt < 4; ++nt)
                    acc[mo][nt] = __builtin_amdgcn_mfma_f32_16x16x32_bf16(
                        bb[mo], a[nt], acc[mo][nt], 0, 0, 0);
        }
        const float qs = (f == 0) ? K2 : 1.0f;
        ushort_t* dst = (f == 0 ? q : k) + (size_t)bh * Nc * DKc;
#pragma unroll
        for (int mo = 0; mo < 4; ++mo) {
            const int d0 = mo * 16 + quad * 4;            // 4 consecutive d
            const float4 b4 = *(const float4*)&bp[o0 + d0];
#pragma unroll
            for (int nt = 0; nt < 4; ++nt) {
                const int token = m0 + nt * 16 + l15;
                us4 pk = { f2bf((acc[mo][nt][0] + b4.x) * qs),
                           f2bf((acc[mo][nt][1] + b4.y) * qs),
                           f2bf((acc[mo][nt][2] + b4.z) * qs),
                           f2bf((acc[mo][nt][3] + b4.w) * qs) };
                *(us4*)&dst[(size_t)token * DKc + d0] = pk;
            }
        }
    }
}

// ---------------------------------------------------------------------------
// Kernel 2: partial column sums. spart[split][bh][j] = sum_{i chunk} 2^s.
// 1D grid 512, XCD-swizzled: id = jb*64 + bh*2 + js.
// ---------------------------------------------------------------------------
__global__ __launch_bounds__(256, 2) void stats_kernel(
    const ushort_t* __restrict__ q, const ushort_t* __restrict__ k,
    float* __restrict__ spart)
{
    const int tid = threadIdx.x;
    const int wave = tid >> 6, lane = tid & 63, quad = lane >> 4, l15 = lane & 15;
    const int id = blockIdx.x;
    const int jb = id >> 6;
    const int bh = (id & 63) >> 1;
    const int js = id & 1;
    const int j0 = jb * 256 + wave * 64;
    const int ibase = js * (Nc / NSPLIT_S);
    const ushort_t* K = k + ((size_t)bh * Nc + j0) * DKc;
    const ushort_t* Q = q + (size_t)bh * Nc * DKc;

    sh8 aK[4][2];
#pragma unroll
    for (int mj = 0; mj < 4; ++mj)
#pragma unroll
        for (int kk = 0; kk < 2; ++kk)
            aK[mj][kk] = *(const sh8*)&K[(size_t)(mj * 16 + l15) * DKc + kk * 32 + quad * 8];

    float lsum[4][4] = {};
    for (int it = 0; it < Nc / NSPLIT_S; it += 64) {
        const int i0 = ibase + it;
        sh8 bQ[4][2];
#pragma unroll
        for (int ni = 0; ni < 4; ++ni)
#pragma unroll
            for (int kk = 0; kk < 2; ++kk)
                bQ[ni][kk] = *(const sh8*)&Q[(size_t)(i0 + ni * 16 + l15) * DKc + kk * 32 + quad * 8];
#pragma unroll
        for (int mj = 0; mj < 4; ++mj)
#pragma unroll
            for (int ni = 0; ni < 4; ++ni) {
                f4 s = (f4)0.f;
                s = __builtin_amdgcn_mfma_f32_16x16x32_bf16(aK[mj][0], bQ[ni][0], s, 0, 0, 0);
                s = __builtin_amdgcn_mfma_f32_16x16x32_bf16(aK[mj][1], bQ[ni][1], s, 0, 0, 0);
#pragma unroll
                for (int r = 0; r < 4; ++r)
                    lsum[mj][r] += exp2f(s[r]);
            }
    }
#pragma unroll
    for (int mj = 0; mj < 4; ++mj)
#pragma unroll
        for (int r = 0; r < 4; ++r) {
            float v = lsum[mj][r];
            v += __shfl_xor(v, 1); v += __shfl_xor(v, 2);
            v += __shfl_xor(v, 4); v += __shfl_xor(v, 8);
            if (l15 == 0)
                spart[((size_t)js * Bc * Hc + bh) * Nc + j0 + mj * 16 + quad * 4 + r] = v;
        }
}

// vT[bh,d,j] *= 1/(spart0+spart1)[bh,j]  (rcp folded in; one fewer launch)
__global__ __launch_bounds__(256) void vscale_kernel(
    ushort_t* __restrict__ vT, const float* __restrict__ spart)
{
    int i = blockIdx.x * 256 + threadIdx.x;   // us4 index
    int f = i * 4;
    int row = f >> 11;                        // bh*64 + d
    int j = f & 2047;
    int bh = row >> 6;
    const float* sp = spart + (size_t)bh * Nc + j;
    float4 s0 = *(const float4*)sp;
    float4 s1 = *(const float4*)(sp + BHN);
    us4 v = ((us4*)vT)[i];
    us4 o = { f2bf(bf2f(v[0]) / (s0.x + s1.x)), f2bf(bf2f(v[1]) / (s0.y + s1.y)),
              f2bf(bf2f(v[2]) / (s0.z + s1.z)), f2bf(bf2f(v[3]) / (s0.w + s1.w)) };
    ((us4*)vT)[i] = o;
}

// ---------------------------------------------------------------------------
// Kernel 3: partial PV over a j-chunk (unchanged from R5; conflict-free).
// ---------------------------------------------------------------------------
__global__ __launch_bounds__(256, 2) void apply_kernel(
    const ushort_t* __restrict__ q, const ushort_t* __restrict__ k,
    const ushort_t* __restrict__ vT,
    ushort_t* __restrict__ part0, ushort_t* __restrict__ part1)
{
    __shared__ __align__(16) ushort_t Ks[128 * 64];     // 16 KB
    __shared__ __align__(16) ushort_t Vs[64 * 128];     // 16 KB
    __shared__ __align__(16) ushort_t Ps[4][64 * 64];   // 32 KB per-wave
    const int tid = threadIdx.x;
    const int wave = tid >> 6, lane = tid & 63, quad = lane >> 4, l15 = lane & 15;
    const int id = blockIdx.x;
    const int ibk = id >> 6;
    const int bh = (id & 63) >> 1;
    const int js = id & 1;
    const int b = bh >> 3, h = bh & 7;
    const int i0 = ibk * 256 + wave * 64;
    const int jbase = js * (Nc / 2);
    const ushort_t* Q  = q  + ((size_t)bh * Nc + i0) * DKc;
    const ushort_t* Kb = k  + (size_t)bh * Nc * DKc;
    const ushort_t* Vb = vT + (size_t)bh * DKc * Nc;
    ushort_t* Pw = Ps[wave];
    const int sw = l15 & 7;
    const int hb = (l15 >> 3) & 1;

    sh8 bQ[4][2];
#pragma unroll
    for (int ni = 0; ni < 4; ++ni)
#pragma unroll
        for (int kk = 0; kk < 2; ++kk)
            bQ[ni][kk] = *(const sh8*)&Q[(size_t)(ni * 16 + l15) * DKc + kk * 32 + quad * 8];

    f4 acc[4][4];
#pragma unroll
    for (int i = 0; i < 4; ++i)
#pragma unroll
        for (int j = 0; j < 4; ++j) acc[i][j] = (f4)0.f;

    int koff[4], voff[4], lbase[4];
#pragma unroll
    for (int c = 0; c < 4; ++c) {
        int g = c * 256 + tid;
        int rk = g >> 3, ck = (g & 7) ^ (rk & 7);
        koff[c] = rk * DKc + ck * 8;
        int rv = g >> 4, cs = g & 15, cn = (cs & 8) | ((cs & 7) ^ (rv & 7));
        voff[c] = rv * Nc + cn * 8;
        lbase[c] = (c * 256 + wave * 64) * 8;
    }

    for (int st = 0; st < 8; ++st) {
        const int j0 = jbase + st * 128;
#pragma unroll
        for (int c = 0; c < 4; ++c) {
            gl_lds16(Kb + (size_t)j0 * DKc + koff[c], Ks + lbase[c]);
            gl_lds16(Vb + voff[c] + j0,               Vs + lbase[c]);
        }
        __syncthreads();

#pragma unroll
        for (int jj = 0; jj < 128; jj += 64) {
            sh8 aK[4][2];
#pragma unroll
            for (int mj = 0; mj < 4; ++mj)
#pragma unroll
                for (int kk = 0; kk < 2; ++kk)
                    aK[mj][kk] = *(const sh8*)&Ks[(jj + mj * 16 + l15) * 64 +
                                                  (((kk * 4 + quad) ^ sw) << 3)];
#pragma unroll
            for (int ni = 0; ni < 4; ++ni) {
                const int prow = ni * 16 + l15;
#pragma unroll
                for (int mj = 0; mj < 4; ++mj) {
                    f4 s = (f4)0.f;
                    s = __builtin_amdgcn_mfma_f32_16x16x32_bf16(aK[mj][0], bQ[ni][0], s, 0, 0, 0);
                    s = __builtin_amdgcn_mfma_f32_16x16x32_bf16(aK[mj][1], bQ[ni][1], s, 0, 0, 0);
                    unsigned e0 = fbits(exp2f(s[0]));
                    unsigned e1 = fbits(exp2f(s[1]));
                    unsigned e2 = fbits(exp2f(s[2]));
                    unsigned e3 = fbits(exp2f(s[3]));
                    uint2 pk;
                    pk.x = __builtin_amdgcn_perm(e1, e0, 0x07060302u);
                    pk.y = __builtin_amdgcn_perm(e3, e2, 0x07060302u);
                    const int off = prow * 64 + ((((mj * 2 + (quad >> 1)) ^ sw)) << 3)
                                  + (((quad & 1) ^ hb) << 2);
                    *(uint2*)&Pw[off] = pk;
                }
            }
#pragma unroll
            for (int kk = 0; kk < 2; ++kk) {
                const int cgk = (((kk * 4 + quad) ^ sw)) << 3;
                const int h0 = hb << 2, h1 = 4 - h0;
                sh8 aP[4], bV[4];
#pragma unroll
                for (int mi = 0; mi < 4; ++mi) {
                    union { sh8 s8; uint2 u[2]; } t;
                    const int rb = (mi * 16 + l15) * 64 + cgk;
                    t.u[0] = *(const uint2*)&Pw[rb + h0];
                    t.u[1] = *(const uint2*)&Pw[rb + h1];
                    aP[mi] = t.s8;
                }
                const int gnat = (jj >> 3) + kk * 4 + quad;
                const int vcg = ((gnat & 8) | ((gnat & 7) ^ sw)) << 3;
#pragma unroll
                for (int nd = 0; nd < 4; ++nd)
                    bV[nd] = *(const sh8*)&Vs[(nd * 16 + l15) * 128 + vcg];
#pragma unroll
                for (int mi = 0; mi < 4; ++mi)
#pragma unroll
                    for (int nd = 0; nd < 4; ++nd)
                        acc[mi][nd] = __builtin_amdgcn_mfma_f32_16x16x32_bf16(
                            aP[mi], bV[nd], acc[mi][nd], 0, 0, 0);
            }
        }
        __syncthreads();
    }

    ushort_t* part = js ? part1 : part0;
    ushort_t* dst = part + ((size_t)b * Nc + i0) * Cc + h * DKc;
#pragma unroll
    for (int mi = 0; mi < 4; ++mi)
#pragma unroll
        for (int nd = 0; nd < 4; ++nd)
#pragma unroll
            for (int r = 0; r < 4; ++r)
                dst[(size_t)(mi * 16 + quad * 4 + r) * Cc + nd * 16 + l15] =
                    f2bf(acc[mi][nd][r]);
}

// res (== part1 in-place) = bf16( fp32(part0) + fp32(part1) )
__global__ __launch_bounds__(256) void reduce_kernel(
    const ushort_t* __restrict__ p0, ushort_t* __restrict__ p1res)
{
    int i = blockIdx.x * 256 + threadIdx.x;
    us4 a = ((const us4*)p0)[i];
    us4 b = ((const us4*)p1res)[i];
    us4 o;
#pragma unroll
    for (int j = 0; j < 4; ++j)
        o[j] = f2bf(bf2f(a[j]) + bf2f(b[j]));
    ((us4*)p1res)[i] = o;
}

// ---------------------------------------------------------------------------
// Kernel 4: out[b,co,n] = res @ Wo^T + bo + x
// ---------------------------------------------------------------------------
__global__ __launch_bounds__(256) void out_kernel(
    const ushort_t* __restrict__ res, const ushort_t* __restrict__ Wob,
    const float* __restrict__ bo, const float* __restrict__ x,
    float* __restrict__ out)
{
    const int tid = threadIdx.x;
    const int wave = tid >> 6, lane = tid & 63, quad = lane >> 4, l15 = lane & 15;
    const int m0  = blockIdx.x * 128 + (wave & 1) * 64;
    const int co0 = blockIdx.y * 128 + (wave >> 1) * 64;
    const ushort_t* A  = res + (size_t)m0 * Cc;
    const ushort_t* Bw = Wob + (size_t)co0 * Cc;

    f4 acc[4][4];
#pragma unroll
    for (int i = 0; i < 4; ++i)
#pragma unroll
        for (int j = 0; j < 4; ++j) acc[i][j] = (f4)0.f;

    for (int kk = 0; kk < Cc; kk += 32) {
        sh8 a[4], bb[4];
#pragma unroll
        for (int mi = 0; mi < 4; ++mi)
            a[mi] = *(const sh8*)&A[(size_t)(mi * 16 + l15) * Cc + kk + quad * 8];
#pragma unroll
        for (int ni = 0; ni < 4; ++ni)
            bb[ni] = *(const sh8*)&Bw[(size_t)(ni * 16 + l15) * Cc + kk + quad * 8];
#pragma unroll
        for (int mi = 0; mi < 4; ++mi)
#pragma unroll
            for (int ni = 0; ni < 4; ++ni)
                acc[mi][ni] = __builtin_amdgcn_mfma_f32_16x16x32_bf16(
                    a[mi], bb[ni], acc[mi][ni], 0, 0, 0);
    }

    const int b = m0 >> 11;
    const int n_base = m0 & 2047;
#pragma unroll
    for (int ni = 0; ni < 4; ++ni) {
        const int co = co0 + ni * 16 + l15;
        const float bias = bo[co];
#pragma unroll
        for (int mi = 0; mi < 4; ++mi) {
            const int n = n_base + mi * 16 + quad * 4;
            const size_t idx = ((size_t)b * Cc + co) * Nc + n;
            float4 xr = *(const float4*)&x[idx];
            float4 o;
            o.x = acc[mi][ni][0] + bias + xr.x;
            o.y = acc[mi][ni][1] + bias + xr.y;
            o.z = acc[mi][ni][2] + bias + xr.z;
            o.w = acc[mi][ni][3] + bias + xr.w;
            *(float4*)&out[idx] = o;
        }
    }
}

// ---------------------------------------------------------------------------
extern "C" void kernel_launch(void* const* d_in, const int* in_sizes, int n_in,
                              void* d_out, int out_size, void* d_ws, size_t ws_size,
                              hipStream_t stream)
{
    const float* x  = (const float*)d_in[0];
    const float* Wp = (const float*)d_in[1];
    const float* bp = (const float*)d_in[2];
    const float* Wo = (const float*)d_in[3];
    const float* bo = (const float*)d_in[4];
    float* out = (float*)d_out;

    float* coef  = (float*)d_ws;                              // (unused slot, kept for layout)
    float* spart = coef + BHN;                                // NSPLIT_S * BHN
    ushort_t* wsb = (ushort_t*)(spart + (size_t)NSPLIT_S * BHN);
    const size_t nE = (size_t)Bc * Nc * Cc;                   // 4,194,304
    ushort_t* xt  = wsb;                 // also part0 (dead after qkv)
    ushort_t* Wpb = xt  + nE;
    ushort_t* Wob = Wpb + (size_t)O3c * Cc;
    ushort_t* qw  = Wob + (size_t)Cc * Cc;
    ushort_t* kw  = qw + nE;
    ushort_t* vT  = kw + nE;
    ushort_t* res = vT + nE;             // also part1

    xpose_kernel<<<dim3(Nc / 32, Cc / 32, Bc), 256, 0, stream>>>(x, xt);
    cvt_kernel<<<dim3((O3c * Cc / 4 + 255) / 256), 256, 0, stream>>>(Wp, Wpb, O3c * Cc / 4);
    cvt_kernel<<<dim3((Cc * Cc / 4 + 255) / 256), 256, 0, stream>>>(Wo, Wob, Cc * Cc / 4);
    qkv_kernel<<<dim3(O3c / 128, Nc / 128, Bc), 256, 0, stream>>>(xt, Wpb, bp, qw, kw, vT);
    stats_kernel<<<dim3(512), 256, 0, stream>>>(qw, kw, spart);
    vscale_kernel<<<dim3((int)(nE / 4 / 256)), 256, 0, stream>>>(vT, spart);
    apply_kernel<<<dim3(512), 256, 0, stream>>>(qw, kw, vT, xt, res);
    reduce_kernel<<<dim3((int)(nE / 4 / 256)), 256, 0, stream>>>(xt, res);
    out_kernel<<<dim3(Bc * Nc / 128, Cc / 128), 256, 0, stream>>>(res, Wob, bo, x, out);
}